// Round 8
// baseline (1200.344 us; speedup 1.0000x reference)
//
#include <hip/hip_runtime.h>
#include <stdint.h>
#include <math.h>

typedef unsigned int u32;
typedef unsigned long long u64;
typedef double d4 __attribute__((ext_vector_type(4)));
typedef _Float16 h8 __attribute__((ext_vector_type(8)));
typedef float f32x16 __attribute__((ext_vector_type(16)));

#define NPX    3800        // 50*76
#define NANCH  34200       // NPX*9
#define NSEL   6000
#define NOUT   300
#define NPXP   4160        // 52*80 zero-padded pixel grid (y:-1..50, x:-2..77)

// ---- workspace layout (bytes) ----
#define OFF_T        0ull
#define OFF_WTH      62259200ull
#define OFF_WTL      66977792ull
#define OFF_BOXES    71696384ull
#define OFF_ITEMS    76073984ull
#define OFF_FSPH     78262784ull
#define OFF_FSPL     112341504ull
#define WS_NEED_F16  146551296ull
#define OFF_PART     OFF_FSPH
#define WS_NEED_SPLITK (OFF_PART + 43776000ull)

#define GLL16(gsrc, ldst) \
    __builtin_amdgcn_global_load_lds((const __attribute__((address_space(1))) void*)(gsrc), \
                                     (__attribute__((address_space(3))) void*)(ldst), 16, 0, 0)

// ============================================================
// Kernel P (fused prep): wsplit + fsplit + pad-zero in one dispatch.
// ============================================================
__global__ __launch_bounds__(256) void prep_kernel(const float* __restrict__ feat,
                                                   const float* __restrict__ cw,
                                                   _Float16* __restrict__ wh,
                                                   _Float16* __restrict__ wl,
                                                   _Float16* __restrict__ fh,
                                                   _Float16* __restrict__ fl) {
    const int bid = blockIdx.x;
    const int tid = threadIdx.x;
    __shared__ __align__(16) _Float16 shh[64][32];
    __shared__ __align__(16) _Float16 shl[64][32];

    if (bid < 9216) {
        // ---- wsplit: o in [0, 9*512*512), exact fit
        int o = bid * 256 + tid;
        int ci = o & 511;
        int co = (o >> 9) & 511;
        int kk = o >> 18;
        float v = cw[(((co << 9) + ci) * 9) + kk] * 1024.0f;
        _Float16 h = (_Float16)v;
        float r = v - (float)h;           // exact (Sterbenz)
        wh[o] = h;
        wl[o] = (_Float16)r;
    } else if (bid < 9216 + 7680) {
        // ---- fsplit
        int idx = bid - 9216;
        const int pb = idx % 60; idx /= 60;
        const int b  = idx >> 4;
        const int ci0 = (idx & 15) << 5;
        const int p0  = pb << 6;
        {
            const int r = tid >> 3, xg = tid & 7;     // ci row, 8-px group
            const int p = p0 + (xg << 3);
            float v[8];
            if (p < NPX) {                            // 3800 % 8 == 0
                const float* sp = feat + ((size_t)(b * 512 + ci0 + r)) * NPX + p;
                #pragma unroll
                for (int j = 0; j < 8; ++j) v[j] = sp[j];
            } else {
                #pragma unroll
                for (int j = 0; j < 8; ++j) v[j] = 0.f;
            }
            #pragma unroll
            for (int j = 0; j < 8; ++j) {
                float s = v[j] * 512.0f;
                _Float16 h = (_Float16)s;
                float rr = s - (float)h;
                shh[(xg << 3) + j][r] = h;
                shl[(xg << 3) + j][r] = (_Float16)rr;
            }
        }
        __syncthreads();
        {
            const int px = tid >> 2, cg = tid & 3;
            const int p = p0 + px;
            if (p < NPX) {
                const int yy = p / 76, xx = p - yy * 76;
                const size_t dst = ((size_t)b * NPXP + (size_t)((yy + 1) * 80 + xx + 2)) * 512
                                 + ci0 + (cg << 3);
                *(h8*)(fh + dst) = *(const h8*)&shh[px][cg << 3];
                *(h8*)(fl + dst) = *(const h8*)&shl[px][cg << 3];
            }
        }
    } else {
        // ---- padzero: 2880 cell-tasks x 4 sub-threads (45 blocks exact)
        int idx = (bid - 16896) * 256 + tid;
        int task = idx >> 2, sub = idx & 3;
        if (task < 2880) {
            int b = task / 360, c = task - b * 360;
            int yp, xp;
            if      (c < 80)  { yp = 0;  xp = c; }
            else if (c < 160) { yp = 51; xp = c - 80; }
            else { int c2 = c - 160; yp = 1 + (c2 >> 2); int m = c2 & 3; xp = (m < 2) ? m : (76 + m); }
            const size_t base = ((size_t)b * NPXP + (size_t)(yp * 80 + xp)) * 512 + sub * 128;
            h8 z = {};
            #pragma unroll
            for (int j = 0; j < 16; ++j) {
                *(h8*)(fh + base + (j << 3)) = z;
                *(h8*)(fl + base + (j << 3)) = z;
            }
        }
    }
}

// ============================================================
// Kernel 1 (v8): 3x3 conv, double-f16 MFMA emulation.
// r4<->r7 lesson: occupancy isn't the lever, BARRIER ALIGNMENT is. In
// both, every resident wave drains vmcnt+barrier together -> MFMA pipe
// idles during the post-barrier LDS burst.
// v8: keep the proven 64x64 wave tile (232 regs -> 2 waves/SIMD) but
// in 4-wave 256-thr blocks (128co x 128px, 2x2 grid), ring-4 x 16KB =
// 64KB LDS -> TWO blocks/CU, each SIMD hosts one wave from EACH block.
// Independent barriers: while block A drains, block B's wave on the
// same SIMD keeps issuing MFMAs (anti-phase covers the drain bubble).
// MFMA order product-major round-robin over quadrants (dep spacing 4;
// per-element add order hh,hl,lh and drain cadence unchanged ->
// bitwise-same t vs r2-r7).
// ============================================================
__global__ __launch_bounds__(256, 2) void conv3x3_f16_kernel(
    const _Float16* __restrict__ fh, const _Float16* __restrict__ fl,
    const _Float16* __restrict__ wh, const _Float16* __restrict__ wl,
    const float* __restrict__ bias, float* __restrict__ t)
{
    const int id  = blockIdx.x;            // 1024 blocks
    const int b   = id & 7;                // b == XCD (dispatch round-robins id%8)
    const int g   = id >> 3;               // 0..127
    const int co0 = (g >> 5) << 7;         // 4 co-blocks of 128 (co-major: weight L2 reuse)
    const int pt0 = (g & 31) << 7;         // 32 px-blocks of 128 -> p' 0..4095
    const int tid = threadIdx.x;
    const int w   = tid >> 6;              // 0..3
    const int l   = tid & 63;
    const int wm  = w >> 1, wn = w & 1;    // 2x2 wave grid -> wave tile 64co x 64px
    const int ln  = l & 31, lk = l >> 5;

    __shared__ __align__(16) _Float16 S[4][16][512];   // 64 KB: ring of 4 step-slots
    // per slot: tiles 0..7 = A (mt*2+hl, 128 co), 8..15 = B (nt*2+hl, 128 px)

    // stage bases: wave w stages tiles 4w..4w+3 (waves 0-1: A, waves 2-3: B)
    const _Float16* sb[4];
    u32 ldof[4];
    const long long fbase = (long long)b * NPXP + pt0;
    #pragma unroll
    for (int i = 0; i < 4; ++i) {
        const int ti = (w << 2) + i;
        ldof[i] = (u32)(ti * 1024 + l * 16);
        if (ti < 8) {
            const int mt = ti >> 1, hl = ti & 1;
            sb[i] = (hl ? wl : wh) + ((long long)(co0 + (mt << 5) + ln) << 9) + (lk << 3);
        } else {
            const int tj = ti - 8, nt = tj >> 1, hl = tj & 1;
            sb[i] = (hl ? fl : fh) + ((fbase + (nt << 5) + ln) << 9) + (lk << 3);
        }
    }
    char* lbase = (char*)&S[0][0][0];

    auto stage = [&](int q, int slot) {
        const int kk  = q >> 5;                    // 0..8 wave-uniform
        const int ci0 = (q & 31) << 4;
        long long off;
        if (w < 2) {
            off = ((long long)kk << 18) + ci0;     // f16 units
        } else {
            const int kd = (kk * 11) >> 5;         // kk/3
            const int s  = kd * 77 + kk - 81;      // dy*80 + dx
            off = ((long long)s << 9) + ci0;
        }
        char* ld = lbase + slot * 16384;
        #pragma unroll
        for (int i = 0; i < 4; ++i)
            GLL16(sb[i] + off, ld + ldof[i]);
    };

    f32x16 acc[2][2], l2[2][2];
    #pragma unroll
    for (int i = 0; i < 2; ++i)
        #pragma unroll
        for (int j = 0; j < 2; ++j)
            #pragma unroll
            for (int gg = 0; gg < 16; ++gg) { acc[i][j][gg] = 0.0f; l2[i][j][gg] = 0.0f; }

    const int ao = l << 3;   // f16 units: lane-linear fragment slice (HW-verified r1)

    auto readFrags = [&](int slot, h8* Ah, h8* Al, h8* Bh, h8* Bl) {
        const _Float16* Sq = (const _Float16*)(lbase + slot * 16384);
        #pragma unroll
        for (int i = 0; i < 2; ++i) {
            const int mt = (wm << 1) + i, nt = (wn << 1) + i;
            Ah[i] = *(const h8*)(Sq + (((mt << 1) + 0) << 9) + ao);
            Al[i] = *(const h8*)(Sq + (((mt << 1) + 1) << 9) + ao);
            Bh[i] = *(const h8*)(Sq + ((8 + (nt << 1) + 0) << 9) + ao);
            Bl[i] = *(const h8*)(Sq + ((8 + (nt << 1) + 1) << 9) + ao);
        }
    };

    // 12 MFMAs of one step, product-major round-robin over the 4 quadrants
    // (per-element order stays hh, hl, lh -> bitwise-identical accumulation)
    auto step12 = [&](h8* Ah, h8* Al, h8* Bh, h8* Bl) {
        acc[0][0] = __builtin_amdgcn_mfma_f32_32x32x16_f16(Ah[0], Bh[0], acc[0][0], 0, 0, 0);
        acc[0][1] = __builtin_amdgcn_mfma_f32_32x32x16_f16(Ah[0], Bh[1], acc[0][1], 0, 0, 0);
        acc[1][0] = __builtin_amdgcn_mfma_f32_32x32x16_f16(Ah[1], Bh[0], acc[1][0], 0, 0, 0);
        acc[1][1] = __builtin_amdgcn_mfma_f32_32x32x16_f16(Ah[1], Bh[1], acc[1][1], 0, 0, 0);
        acc[0][0] = __builtin_amdgcn_mfma_f32_32x32x16_f16(Ah[0], Bl[0], acc[0][0], 0, 0, 0);
        acc[0][1] = __builtin_amdgcn_mfma_f32_32x32x16_f16(Ah[0], Bl[1], acc[0][1], 0, 0, 0);
        acc[1][0] = __builtin_amdgcn_mfma_f32_32x32x16_f16(Ah[1], Bl[0], acc[1][0], 0, 0, 0);
        acc[1][1] = __builtin_amdgcn_mfma_f32_32x32x16_f16(Ah[1], Bl[1], acc[1][1], 0, 0, 0);
        acc[0][0] = __builtin_amdgcn_mfma_f32_32x32x16_f16(Al[0], Bh[0], acc[0][0], 0, 0, 0);
        acc[0][1] = __builtin_amdgcn_mfma_f32_32x32x16_f16(Al[0], Bh[1], acc[0][1], 0, 0, 0);
        acc[1][0] = __builtin_amdgcn_mfma_f32_32x32x16_f16(Al[1], Bh[0], acc[1][0], 0, 0, 0);
        acc[1][1] = __builtin_amdgcn_mfma_f32_32x32x16_f16(Al[1], Bh[1], acc[1][1], 0, 0, 0);
    };

    // prologue: fill ring slots 0,1; drain; barrier
    stage(0, 0); stage(1, 1);
    asm volatile("s_waitcnt vmcnt(0)" ::: "memory");
    __builtin_amdgcn_sched_barrier(0);
    __builtin_amdgcn_s_barrier();

    int s0 = 0;   // slot of step q0 = 2F  (XOR ring: s0 ^= 2 per frame)
    for (int F = 0; F < 144; ++F) {
        const int q0 = F << 1;
        const int s1 = s0 ^ 1;
        const int s2 = s0 ^ 2;
        const int s3 = s0 ^ 3;
        // stage into the slots frame F-1 just read (safe after F-1's end barrier)
        if (q0 + 2 < 288) stage(q0 + 2, s2);
        if (q0 + 3 < 288) stage(q0 + 3, s3);

        h8 A0h[2], A0l[2], B0h[2], B0l[2];
        h8 A1h[2], A1l[2], B1h[2], B1l[2];
        readFrags(s0, A0h, A0l, B0h, B0l);
        __builtin_amdgcn_s_setprio(1);
        step12(A0h, A0l, B0h, B0l);            // step q0
        __builtin_amdgcn_s_setprio(0);
        readFrags(s1, A1h, A1l, B1h, B1l);     // flies under other block's MFMAs
        __builtin_amdgcn_s_setprio(1);
        step12(A1h, A1l, B1h, B1l);            // step q0+1
        __builtin_amdgcn_s_setprio(0);

        if (((q0 + 1) & 7) == 7) {   // two-level f32 cascade drain (same cadence as r2-r7)
            #pragma unroll
            for (int i = 0; i < 2; ++i)
                #pragma unroll
                for (int j = 0; j < 2; ++j) {
                    l2[i][j] += acc[i][j];
                    #pragma unroll
                    for (int gg = 0; gg < 16; ++gg) acc[i][j][gg] = 0.0f;
                }
        }

        if (F < 143) {
            __builtin_amdgcn_sched_barrier(0);
            asm volatile("s_waitcnt vmcnt(0)" ::: "memory");   // GLLs had the whole frame
            __builtin_amdgcn_sched_barrier(0);
            __builtin_amdgcn_s_barrier();
            __builtin_amdgcn_sched_barrier(0);
        }
        s0 ^= 2;
    }

    // runtime D-layout probe (verified in round-1; never trust the doc mapping)
    int rcp[16];
    {
        h8 pa, pb;
        #pragma unroll
        for (int j = 0; j < 8; ++j) { pa[j] = (_Float16)(float)ln; pb[j] = (_Float16)0.0625f; }
        f32x16 pr, pc;
        #pragma unroll
        for (int gg = 0; gg < 16; ++gg) { pr[gg] = 0.0f; pc[gg] = 0.0f; }
        pr = __builtin_amdgcn_mfma_f32_32x32x16_f16(pa, pb, pr, 0, 0, 0);  // D[m][n] = m
        pc = __builtin_amdgcn_mfma_f32_32x32x16_f16(pb, pa, pc, 0, 0, 0);  // D[m][n] = n
        #pragma unroll
        for (int gg = 0; gg < 16; ++gg)
            rcp[gg] = ((int)(pr[gg] + 0.5f)) | (((int)(pc[gg] + 0.5f)) << 8);
    }

    const double dsc = 1.0 / 524288.0;   // 1/(1024*512) exact descale
    #pragma unroll
    for (int i = 0; i < 2; ++i) {
        #pragma unroll
        for (int j = 0; j < 2; ++j) {
            #pragma unroll
            for (int gg = 0; gg < 16; ++gg) {
                const int row = rcp[gg] & 255;
                const int col = rcp[gg] >> 8;
                const int co  = co0 + (wm << 6) + (i << 5) + row;
                const int pp  = pt0 + (wn << 6) + (j << 5) + col;
                const int yy  = pp / 80;
                const int xx  = pp - yy * 80;
                if (yy >= 1 && yy < 51 && xx >= 2 && xx < 78) {
                    const double v = (double)l2[i][j][gg] * dsc + (double)bias[co];
                    t[((size_t)(b * 512 + co)) * NPX + (yy - 1) * 76 + (xx - 2)]
                        = (float)(v > 0.0 ? v : 0.0);
                }
            }
        }
    }
}

// ============================================================
// FALLBACK Kernel 0: weight transpose conv_w[co][ci][ky][kx] -> wt[kk][ci][co] (f32)
// ============================================================
__global__ __launch_bounds__(1024) void wtrans_kernel(const float* __restrict__ cw,
                                                      float* __restrict__ wt) {
    int o = blockIdx.x * 1024 + threadIdx.x;
    if (o >= 512*512*9) return;
    int co = o & 511;
    int ci = (o >> 9) & 511;
    int kk = o >> 18;
    wt[o] = cw[((co << 9) + ci) * 9 + kk];
}

// ============================================================
// FALLBACK Kernel 1: f64 MFMA conv (round-7 structure), t stored f32
// ============================================================
__global__ __launch_bounds__(256, 2) void conv3x3_mfma_kernel(const float* __restrict__ feat,
                                                              const float* __restrict__ wt,
                                                              const float* __restrict__ bias,
                                                              float* __restrict__ t) {
    const int b   = blockIdx.z;
    const int co0 = blockIdx.y << 7;
    const int px0 = blockIdx.x << 6;
    const int tid = threadIdx.x;
    const int w    = tid >> 6;
    const int l    = tid & 63;
    const int quad = l >> 4;
    const int lc   = l & 15;

    __shared__ double BsF[2][1024];

    int rr[4], cc[4];
    {
        d4 pzr = {0.0, 0.0, 0.0, 0.0};
        d4 pzc = {0.0, 0.0, 0.0, 0.0};
        double paM = (double)lc;
        double pbN = (double)lc;
        pzr = __builtin_amdgcn_mfma_f64_16x16x4f64(paM, 1.0, pzr, 0, 0, 0);
        pzc = __builtin_amdgcn_mfma_f64_16x16x4f64(1.0, pbN, pzc, 0, 0, 0);
        #pragma unroll
        for (int g = 0; g < 4; ++g) {
            rr[g] = (((int)pzr[g]) >> 2) & 15;
            cc[g] = (((int)pzc[g]) >> 2) & 15;
        }
    }

    d4 acc[2][4];
    #pragma unroll
    for (int i = 0; i < 2; ++i)
        #pragma unroll
        for (int j = 0; j < 4; ++j) acc[i][j] = (d4){0.0, 0.0, 0.0, 0.0};

    const float* featb = feat + (size_t)b * 512 * NPX;

    const int b_quad = (tid >> 4) & 3;
    const int b_pxl  = ((tid >> 6) << 4) | (tid & 15);
    const int p      = px0 + b_pxl;
    const int py     = p / 76;
    const int px     = p - py * 76;
    const bool pvalid = (p < NPX);

    float vaf[8], vbf[4];
    double a_cur[8];

    auto loadA = [&](int q, float* va) {
        int kk  = q >> 5;
        int ci0 = (q & 31) << 4;
        const float* ap = wt + (((size_t)(kk * 512 + ci0 + quad)) << 9)
                             + co0 + (w << 5) + lc;
        #pragma unroll
        for (int ks = 0; ks < 4; ++ks) {
            va[ks * 2 + 0] = ap[(ks << 11)];
            va[ks * 2 + 1] = ap[(ks << 11) + 16];
        }
    };
    auto loadB = [&](int q, float* vb) {
        int kk  = q >> 5;
        int ci0 = (q & 31) << 4;
        int kd = kk / 3;
        int dy = kd - 1, dx = kk - kd * 3 - 1;
        int iy = py + dy, ix = px + dx;
        bool ok = pvalid && ((unsigned)iy < 50u) && ((unsigned)ix < 76u);
        if (ok) {
            const float* bp = featb + (size_t)(ci0 + b_quad) * NPX + iy * 76 + ix;
            #pragma unroll
            for (int j = 0; j < 4; ++j) vb[j] = bp[(size_t)(j << 2) * NPX];
        } else {
            vb[0] = vb[1] = vb[2] = vb[3] = 0.0f;
        }
    };

    loadA(0, vaf); loadB(0, vbf);
    #pragma unroll
    for (int j = 0; j < 4; ++j) BsF[0][tid + (j << 8)] = (double)vbf[j];
    #pragma unroll
    for (int j = 0; j < 8; ++j) a_cur[j] = (double)vaf[j];
    __syncthreads();

    for (int q = 0; q < 288; ++q) {
        const int cur = q & 1;
        if (q < 287) { loadA(q + 1, vaf); loadB(q + 1, vbf); }
        const double* bb = BsF[cur];
        #pragma unroll
        for (int ks = 0; ks < 4; ++ks) {
            const double* bp = bb + (ks << 8);
            double a0 = a_cur[ks * 2], a1 = a_cur[ks * 2 + 1];
            #pragma unroll
            for (int nt = 0; nt < 4; ++nt) {
                double bv = bp[(nt << 6) + l];
                acc[0][nt] = __builtin_amdgcn_mfma_f64_16x16x4f64(a0, bv, acc[0][nt], 0, 0, 0);
                acc[1][nt] = __builtin_amdgcn_mfma_f64_16x16x4f64(a1, bv, acc[1][nt], 0, 0, 0);
            }
        }
        if (q < 287) {
            #pragma unroll
            for (int j = 0; j < 4; ++j) BsF[cur ^ 1][tid + (j << 8)] = (double)vbf[j];
            #pragma unroll
            for (int j = 0; j < 8; ++j) a_cur[j] = (double)vaf[j];
            __syncthreads();
        }
    }

    #pragma unroll
    for (int mt = 0; mt < 2; ++mt) {
        #pragma unroll
        for (int g = 0; g < 4; ++g) {
            int co = co0 + (w << 5) + (mt << 4) + rr[g];
            double bs = (double)bias[co];
            float* row = t + ((size_t)b * 512 + co) * NPX;
            #pragma unroll
            for (int nt = 0; nt < 4; ++nt) {
                int pp = px0 + (nt << 4) + cc[g];
                if (pp < NPX) {
                    double v = acc[mt][nt][g] + bs;
                    row[pp] = (float)(v > 0.0 ? v : 0.0);
                }
            }
        }
    }
}

// ============================================================
// Kernel 2a: 1x1 heads, split-K x4 partials (f64 accumulate from f32 t)
// ============================================================
__global__ __launch_bounds__(64) void heads_partial_kernel(const float* __restrict__ t,
                                                           const float* __restrict__ cls_w,
                                                           const float* __restrict__ box_w,
                                                           double* __restrict__ part) {
    const int b = blockIdx.y, c = blockIdx.z;
    const int p = blockIdx.x * 64 + threadIdx.x;
    if (p >= NPX) return;
    const float* tb = t + ((size_t)b * 512 + c * 128) * NPX + p;

    double ac[9]  = {};
    double ab[36] = {};
    for (int ci = 0; ci < 128; ++ci) {
        double tv = (double)tb[(size_t)ci * NPX];
        int cw = c * 128 + ci;
        #pragma unroll
        for (int o = 0; o < 9;  ++o) ac[o] = fma((double)cls_w[o * 512 + cw], tv, ac[o]);
        #pragma unroll
        for (int o = 0; o < 36; ++o) ab[o] = fma((double)box_w[o * 512 + cw], tv, ab[o]);
    }
    double* dst = part + ((size_t)(c * 8 + b) * 45) * NPX + p;
    #pragma unroll
    for (int o = 0; o < 9;  ++o) dst[(size_t)o * NPX] = ac[o];
    #pragma unroll
    for (int o = 0; o < 36; ++o) dst[(size_t)(9 + o) * NPX] = ab[o];
}

// shared decode body
__device__ __forceinline__ void decode_px(int b, int p, const double* s45,
                                          const float* cls_b, const float* box_b,
                                          float* out_obj, float* out_del,
                                          float* boxes, u64* items) {
    float* ob = out_obj + (size_t)b * NANCH + (size_t)p * 9;
    float* dl = out_del + (size_t)b * NANCH * 4 + (size_t)p * 36;
    const int yy = p / 76, xx = p - yy * 76;

    #pragma unroll
    for (int a = 0; a < 9; ++a) {
        double s  = s45[a] + (double)cls_b[a];
        ob[a] = (float)s;
        double d0 = s45[9 + 4*a + 0] + (double)box_b[4*a+0];
        double d1 = s45[9 + 4*a + 1] + (double)box_b[4*a+1];
        double d2 = s45[9 + 4*a + 2] + (double)box_b[4*a+2];
        double d3 = s45[9 + 4*a + 3] + (double)box_b[4*a+3];
        dl[4*a+0] = (float)d0; dl[4*a+1] = (float)d1;
        dl[4*a+2] = (float)d2; dl[4*a+3] = (float)d3;

        int si = a / 3, ri = a - si * 3;
        double sz = (si == 0) ? 128.0 : ((si == 1) ? 256.0 : 512.0);
        double hr = (ri == 0) ? 0.7071067811865476 : ((ri == 1) ? 1.0 : 1.4142135623730951);
        float bx2f = (float)(sz / hr * 0.5);
        float by2f = (float)(sz * hr * 0.5);

        double sx = (double)(xx * 16), sy = (double)(yy * 16);
        double x1 = sx - (double)bx2f, x2 = sx + (double)bx2f;
        double y1 = sy - (double)by2f, y2 = sy + (double)by2f;

        double wa = x2 - x1, ha = y2 - y1;
        double cxa = x1 + 0.5 * wa, cya = y1 + 0.5 * ha;
        double cx = d0 * wa + cxa, cy = d1 * ha + cya;
        double w  = exp(d2) * wa,  h  = exp(d3) * ha;

        double px1 = cx - 0.5 * w, py1 = cy - 0.5 * h;
        double px2 = cx + 0.5 * w, py2 = cy + 0.5 * h;
        px1 = fmin(fmax(px1, 0.0), 1216.0);
        py1 = fmin(fmax(py1, 0.0), 800.0);
        px2 = fmin(fmax(px2, 0.0), 1216.0);
        py2 = fmin(fmax(py2, 0.0), 800.0);

        bool keep = ((px2 - px1) >= 16.0) && ((py2 - py1) >= 16.0);
        double se = keep ? s : -INFINITY;

        u64 ubits = (u64)__double_as_longlong(se);
        u64 ka = (ubits >> 63) ? ~ubits : (ubits | 0x8000000000000000ull);
        u64 kd = ~ka;
        int n = p * 9 + a;
        items[(size_t)b * NANCH + n] = (kd & ~0xFFFFull) | (u64)(u32)n;
        *(float4*)(boxes + ((size_t)b * NANCH + n) * 4) =
            make_float4((float)px1, (float)py1, (float)px2, (float)py2);
    }
}

// ============================================================
// Kernel 2b: reduce partials (c ascending, deterministic) + decode
// ============================================================
__global__ __launch_bounds__(64) void reduce_decode_kernel(const double* __restrict__ part,
                                                           const float* __restrict__ cls_b,
                                                           const float* __restrict__ box_b,
                                                           float* __restrict__ out_obj,
                                                           float* __restrict__ out_del,
                                                           float* __restrict__ boxes,
                                                           u64* __restrict__ items) {
    const int b = blockIdx.y;
    const int p = blockIdx.x * 64 + threadIdx.x;
    if (p >= NPX) return;
    double s45[45];
    #pragma unroll
    for (int o = 0; o < 45; ++o) {
        double s = part[((size_t)(0 * 8 + b) * 45 + o) * NPX + p];
        s += part[((size_t)(1 * 8 + b) * 45 + o) * NPX + p];
        s += part[((size_t)(2 * 8 + b) * 45 + o) * NPX + p];
        s += part[((size_t)(3 * 8 + b) * 45 + o) * NPX + p];
        s45[o] = s;
    }
    decode_px(b, p, s45, cls_b, box_b, out_obj, out_del, boxes, items);
}

// ============================================================
// Kernel 2-fallback: single-stage heads+decode (if ws too small)
// ============================================================
__global__ __launch_bounds__(256) void heads_decode_kernel(const float* __restrict__ t,
                                                           const float* __restrict__ cls_w,
                                                           const float* __restrict__ cls_b,
                                                           const float* __restrict__ box_w,
                                                           const float* __restrict__ box_b,
                                                           float* __restrict__ out_obj,
                                                           float* __restrict__ out_del,
                                                           float* __restrict__ boxes,
                                                           u64* __restrict__ items) {
    const int b = blockIdx.y;
    const int p = blockIdx.x * 256 + threadIdx.x;
    if (p >= NPX) return;
    const float* tb = t + (size_t)b * 512 * NPX + p;
    double s45[45];
    #pragma unroll
    for (int o = 0; o < 45; ++o) s45[o] = 0.0;
    for (int ci = 0; ci < 512; ++ci) {
        double tv = (double)tb[(size_t)ci * NPX];
        #pragma unroll
        for (int o = 0; o < 9;  ++o) s45[o]     = fma((double)cls_w[o * 512 + ci], tv, s45[o]);
        #pragma unroll
        for (int o = 0; o < 36; ++o) s45[9 + o] = fma((double)box_w[o * 512 + ci], tv, s45[9 + o]);
    }
    decode_px(b, p, s45, cls_b, box_b, out_obj, out_del, boxes, items);
}

// ============================================================
// IoU > 0.7 test (f32, matches reference formula)
// ============================================================
__device__ __forceinline__ bool iou_gt(float4 A, float4 B, float areaA, float areaB) {
    float ix1 = fmaxf(A.x, B.x), iy1 = fmaxf(A.y, B.y);
    float ix2 = fminf(A.z, B.z), iy2 = fminf(A.w, B.w);
    float iw = fmaxf(ix2 - ix1, 0.0f), ih = fmaxf(iy2 - iy1, 0.0f);
    float inter = iw * ih;
    float uni = areaA + areaB - inter;
    float iou = (uni > 0.0f) ? (inter / uni) : 0.0f;
    return iou > 0.7f;
}

// ============================================================
// Kernel 3: fused top-6000 select + bitonic sort + serial-scan NMS
// ============================================================
__global__ __launch_bounds__(1024) void topk_nms_kernel(const u64* __restrict__ items,
                                                        const float* __restrict__ boxes,
                                                        float* __restrict__ out) {
    extern __shared__ u64 buf[];
    u32* hist = (u32*)buf;
    u32* scan = hist + 4096;
    u32* scal = hist + 5120;

    const int b   = blockIdx.x;
    const int tid = threadIdx.x;
    const u64* it = items + (size_t)b * NANCH;

    #pragma unroll
    for (int i = 0; i < 4; ++i) hist[tid * 4 + i] = 0;
    __syncthreads();
    for (int i = tid; i < NANCH; i += 1024)
        atomicAdd(&hist[(u32)(it[i] >> 52)], 1);
    __syncthreads();

    u32 B1, cum1;
    {
        u32 c0 = hist[tid*4], c1 = hist[tid*4+1], c2 = hist[tid*4+2], c3 = hist[tid*4+3];
        u32 S = c0 + c1 + c2 + c3;
        scan[tid] = S;
        __syncthreads();
        for (int off = 1; off < 1024; off <<= 1) {
            u32 v = (tid >= off) ? scan[tid - off] : 0;
            __syncthreads();
            scan[tid] += v;
            __syncthreads();
        }
        u32 excl = scan[tid] - S;
        const u32 target = 5999;
        if (target >= excl && target < excl + S) {
            u32 pfx = excl, bidx, cum;
            if      (target < pfx + c0)           { bidx = tid*4;   cum = pfx; }
            else if (target < pfx + c0 + c1)      { bidx = tid*4+1; cum = pfx + c0; }
            else if (target < pfx + c0 + c1 + c2) { bidx = tid*4+2; cum = pfx + c0 + c1; }
            else                                  { bidx = tid*4+3; cum = pfx + c0 + c1 + c2; }
            scal[0] = bidx; scal[1] = cum;
        }
    }
    __syncthreads();
    B1 = scal[0]; cum1 = scal[1];
    __syncthreads();

    #pragma unroll
    for (int i = 0; i < 4; ++i) hist[tid * 4 + i] = 0;
    __syncthreads();
    for (int i = tid; i < NANCH; i += 1024) {
        u64 v = it[i];
        if ((u32)(v >> 52) == B1)
            atomicAdd(&hist[(u32)(v >> 40) & 0xFFF], 1);
    }
    __syncthreads();

    u32 B2;
    {
        u32 c0 = hist[tid*4], c1 = hist[tid*4+1], c2 = hist[tid*4+2], c3 = hist[tid*4+3];
        u32 S = c0 + c1 + c2 + c3;
        scan[tid] = S;
        __syncthreads();
        for (int off = 1; off < 1024; off <<= 1) {
            u32 v = (tid >= off) ? scan[tid - off] : 0;
            __syncthreads();
            scan[tid] += v;
            __syncthreads();
        }
        u32 excl = scan[tid] - S;
        const u32 target = 5999 - cum1;
        if (target >= excl && target < excl + S) {
            u32 pfx = excl, bidx;
            if      (target < pfx + c0)           bidx = tid*4;
            else if (target < pfx + c0 + c1)      bidx = tid*4+1;
            else if (target < pfx + c0 + c1 + c2) bidx = tid*4+2;
            else                                  bidx = tid*4+3;
            scal[2] = bidx;
        }
    }
    __syncthreads();
    B2 = scal[2];
    const u32 T = ((B1 << 12) | B2) + 1;
    __syncthreads();

    for (int i = tid; i < 8192; i += 1024) buf[i] = ~0ull;
    __syncthreads();
    u32* cnt = (u32*)&buf[8191];
    if (tid == 0) *cnt = 0;
    __syncthreads();
    for (int i = tid; i < NANCH; i += 1024) {
        u64 v = it[i];
        if ((u32)(v >> 40) < T) {
            u32 pos = atomicAdd(cnt, 1);
            if (pos < 8191) buf[pos] = v;
        }
    }
    __syncthreads();
    if (tid == 0) buf[8191] = ~0ull;
    __syncthreads();

    for (int size = 2; size <= 8192; size <<= 1) {
        for (int stride = size >> 1; stride > 0; stride >>= 1) {
            #pragma unroll
            for (int v = 0; v < 4; ++v) {
                int idx = tid + (v << 10);
                int i = 2 * idx - (idx & (stride - 1));
                int j = i + stride;
                bool up = ((i & size) == 0);
                u64 x = buf[i], y = buf[j];
                if ((x > y) == up) { buf[i] = y; buf[j] = x; }
            }
            __syncthreads();
        }
    }

    float4 bx6[6]; u32 dead6[6];
    #pragma unroll
    for (int s = 0; s < 6; ++s) {
        int r = tid + (s << 10);
        u64 v = buf[r];
        bool dd = (r >= NSEL) || ((u32)(v >> 32) >= 0xFFF00000u);
        float4 bb = make_float4(0.f, 0.f, 0.f, 0.f);
        if (!dd) {
            u32 n = (u32)(v & 0xFFFFull);
            bb = *(const float4*)(boxes + ((size_t)b * NANCH + n) * 4);
        }
        bx6[s] = bb;
        dead6[s] = dd ? 1u : 0u;
    }
    __syncthreads();

    float4* candbox = (float4*)buf;
    u64*    wmask   = (u64*)(buf + 2560);
    float4* accb    = (float4*)(buf + 3072);
    u32*    cntp    = (u32*)(buf + 3712);
    if (tid == 0) *cntp = 0;
    __syncthreads();

    for (int s = 0; s < 6; ++s) {
        int count = (int)*cntp;
        if (count >= NOUT) break;
        float4 mb = bx6[s];
        float  ma = (mb.z - mb.x) * (mb.w - mb.y);
        bool dd = dead6[s] != 0;
        for (int a2 = 0; a2 < count && !dd; ++a2) {
            float4 abx = accb[a2];
            if (iou_gt(mb, abx, ma, (abx.z - abx.x) * (abx.w - abx.y))) dd = true;
        }
        candbox[tid] = mb;
        u64 bal = __ballot(!dd);
        if ((tid & 63) == 0) wmask[tid >> 6] = bal;
        __syncthreads();
        if (tid < 64) {
            int cnt2 = count;
            for (int w2 = 0; w2 < 16 && cnt2 < NOUT; ++w2) {
                u64 mm = wmask[w2];
                while (mm != 0 && cnt2 < NOUT) {
                    int bit = __ffsll(mm) - 1;
                    mm &= (mm - 1);
                    float4 cb = candbox[(w2 << 6) + bit];
                    float  ca = (cb.z - cb.x) * (cb.w - cb.y);
                    bool okc = true;
                    for (int base = count; base < cnt2 && okc; base += 64) {
                        int idx = base + tid;
                        bool bad = false;
                        if (idx < cnt2) {
                            float4 abx = accb[idx];
                            bad = iou_gt(cb, abx, ca, (abx.z - abx.x) * (abx.w - abx.y));
                        }
                        if (__any(bad)) okc = false;
                    }
                    if (okc) {
                        if (tid == 0) accb[cnt2] = cb;
                        cnt2++;
                    }
                }
            }
            if (tid == 0) *cntp = (u32)cnt2;
        }
        __syncthreads();
    }

    int fin = (int)*cntp;
    for (int r = tid; r < NOUT; r += 1024) {
        float4 v = (r < fin) ? accb[r] : make_float4(0.f, 0.f, 0.f, 0.f);
        *(float4*)(out + ((size_t)b * NOUT + r) * 4) = v;
    }
}

// ============================================================
extern "C" void kernel_launch(void* const* d_in, const int* in_sizes, int n_in,
                              void* d_out, int out_size, void* d_ws, size_t ws_size,
                              hipStream_t stream) {
    const float* feat   = (const float*)d_in[0];
    const float* conv_w = (const float*)d_in[1];
    const float* conv_b = (const float*)d_in[2];
    const float* cls_w  = (const float*)d_in[3];
    const float* cls_b  = (const float*)d_in[4];
    const float* box_w  = (const float*)d_in[5];
    const float* box_b  = (const float*)d_in[6];

    float* out       = (float*)d_out;
    float* out_props = out;                       // [8][300][4]
    float* out_obj   = out + 9600;                // [8][34200]
    float* out_del   = out + 9600 + 273600;       // [8][34200][4]

    char* ws = (char*)d_ws;
    float*    t     = (float*)(ws + OFF_T);
    _Float16* wth   = (_Float16*)(ws + OFF_WTH);
    _Float16* wtl   = (_Float16*)(ws + OFF_WTL);
    float*    wtf   = (float*)(ws + OFF_WTH);      // fallback f32 wt (spans hi+lo region)
    float*    boxes = (float*)(ws + OFF_BOXES);
    u64*      items = (u64*)(ws + OFF_ITEMS);
    _Float16* fsph  = (_Float16*)(ws + OFF_FSPH);
    _Float16* fspl  = (_Float16*)(ws + OFF_FSPL);
    double*   part  = (double*)(ws + OFF_PART);

    if (ws_size >= WS_NEED_F16) {
        hipLaunchKernelGGL(prep_kernel, dim3(16941), dim3(256), 0, stream,
                           feat, conv_w, wth, wtl, fsph, fspl);
        hipLaunchKernelGGL(conv3x3_f16_kernel, dim3(1024), dim3(256), 0, stream,
                           fsph, fspl, wth, wtl, conv_b, t);
    } else {
        hipLaunchKernelGGL(wtrans_kernel, dim3(2304), dim3(1024), 0, stream, conv_w, wtf);
        hipLaunchKernelGGL(conv3x3_mfma_kernel, dim3(60, 4, 8), dim3(256), 0, stream,
                           feat, wtf, conv_b, t);
    }
    if (ws_size >= WS_NEED_SPLITK) {
        hipLaunchKernelGGL(heads_partial_kernel, dim3(60, 8, 4), dim3(64), 0, stream,
                           t, cls_w, box_w, part);
        hipLaunchKernelGGL(reduce_decode_kernel, dim3(60, 8), dim3(64), 0, stream,
                           part, cls_b, box_b, out_obj, out_del, boxes, items);
    } else {
        hipLaunchKernelGGL(heads_decode_kernel, dim3(15, 8), dim3(256), 0, stream,
                           t, cls_w, cls_b, box_w, box_b, out_obj, out_del, boxes, items);
    }
    hipLaunchKernelGGL(topk_nms_kernel, dim3(8), dim3(1024), 65536, stream,
                       items, boxes, out_props);
}

// Round 9
// 1092.087 us; speedup vs baseline: 1.0991x; 1.0991x over previous
//
#include <hip/hip_runtime.h>
#include <stdint.h>
#include <math.h>

typedef unsigned int u32;
typedef unsigned long long u64;
typedef double d4 __attribute__((ext_vector_type(4)));
typedef _Float16 h8 __attribute__((ext_vector_type(8)));
typedef float f32x16 __attribute__((ext_vector_type(16)));

#define NPX    3800        // 50*76
#define NANCH  34200       // NPX*9
#define NSEL   6000
#define NOUT   300
#define NPXP   4160        // 52*80 zero-padded pixel grid (y:-1..50, x:-2..77)

// ---- workspace layout (bytes) ----
#define OFF_T        0ull
#define OFF_WTH      62259200ull
#define OFF_WTL      66977792ull
#define OFF_BOXES    71696384ull
#define OFF_ITEMS    76073984ull
#define OFF_FSPH     78262784ull
#define OFF_FSPL     112341504ull
#define WS_NEED_F16  146551296ull
#define OFF_PART     OFF_FSPH
#define WS_NEED_SPLITK (OFF_PART + 43776000ull)

#define GLL16(gsrc, ldst) \
    __builtin_amdgcn_global_load_lds((const __attribute__((address_space(1))) void*)(gsrc), \
                                     (__attribute__((address_space(3))) void*)(ldst), 16, 0, 0)

// ============================================================
// Kernel P (fused prep): wsplit + fsplit + pad-zero in one dispatch.
// (verified absmax-identical across r5-r8)
// ============================================================
__global__ __launch_bounds__(256) void prep_kernel(const float* __restrict__ feat,
                                                   const float* __restrict__ cw,
                                                   _Float16* __restrict__ wh,
                                                   _Float16* __restrict__ wl,
                                                   _Float16* __restrict__ fh,
                                                   _Float16* __restrict__ fl) {
    const int bid = blockIdx.x;
    const int tid = threadIdx.x;
    __shared__ __align__(16) _Float16 shh[64][32];
    __shared__ __align__(16) _Float16 shl[64][32];

    if (bid < 9216) {
        // ---- wsplit: o in [0, 9*512*512), exact fit
        int o = bid * 256 + tid;
        int ci = o & 511;
        int co = (o >> 9) & 511;
        int kk = o >> 18;
        float v = cw[(((co << 9) + ci) * 9) + kk] * 1024.0f;
        _Float16 h = (_Float16)v;
        float r = v - (float)h;           // exact (Sterbenz)
        wh[o] = h;
        wl[o] = (_Float16)r;
    } else if (bid < 9216 + 7680) {
        // ---- fsplit
        int idx = bid - 9216;
        const int pb = idx % 60; idx /= 60;
        const int b  = idx >> 4;
        const int ci0 = (idx & 15) << 5;
        const int p0  = pb << 6;
        {
            const int r = tid >> 3, xg = tid & 7;     // ci row, 8-px group
            const int p = p0 + (xg << 3);
            float v[8];
            if (p < NPX) {                            // 3800 % 8 == 0
                const float* sp = feat + ((size_t)(b * 512 + ci0 + r)) * NPX + p;
                #pragma unroll
                for (int j = 0; j < 8; ++j) v[j] = sp[j];
            } else {
                #pragma unroll
                for (int j = 0; j < 8; ++j) v[j] = 0.f;
            }
            #pragma unroll
            for (int j = 0; j < 8; ++j) {
                float s = v[j] * 512.0f;
                _Float16 h = (_Float16)s;
                float rr = s - (float)h;
                shh[(xg << 3) + j][r] = h;
                shl[(xg << 3) + j][r] = (_Float16)rr;
            }
        }
        __syncthreads();
        {
            const int px = tid >> 2, cg = tid & 3;
            const int p = p0 + px;
            if (p < NPX) {
                const int yy = p / 76, xx = p - yy * 76;
                const size_t dst = ((size_t)b * NPXP + (size_t)((yy + 1) * 80 + xx + 2)) * 512
                                 + ci0 + (cg << 3);
                *(h8*)(fh + dst) = *(const h8*)&shh[px][cg << 3];
                *(h8*)(fl + dst) = *(const h8*)&shl[px][cg << 3];
            }
        }
    } else {
        // ---- padzero: 2880 cell-tasks x 4 sub-threads (45 blocks exact)
        int idx = (bid - 16896) * 256 + tid;
        int task = idx >> 2, sub = idx & 3;
        if (task < 2880) {
            int b = task / 360, c = task - b * 360;
            int yp, xp;
            if      (c < 80)  { yp = 0;  xp = c; }
            else if (c < 160) { yp = 51; xp = c - 80; }
            else { int c2 = c - 160; yp = 1 + (c2 >> 2); int m = c2 & 3; xp = (m < 2) ? m : (76 + m); }
            const size_t base = ((size_t)b * NPXP + (size_t)(yp * 80 + xp)) * 512 + sub * 128;
            h8 z = {};
            #pragma unroll
            for (int j = 0; j < 16; ++j) {
                *(h8*)(fh + base + (j << 3)) = z;
                *(h8*)(fl + base + (j << 3)) = z;
            }
        }
    }
}

// ============================================================
// Kernel 1 (v9 == v4 verbatim): 3x3 conv, double-f16 MFMA emulation.
// Best-measured conv of the session (607 us, r4 bench). Structure:
// ONE 512-thr block (8 waves, 128co x 256px, 2x4 wave grid, 64x64
// wave tile), LDS ring of 5 step-buffers (120 KB), frame = 2 K-steps,
// one barrier per frame, COUNTED s_waitcnt vmcnt(3) at frame tail
// (q0+3 landed, q0+4 in flight), s1 fragment reads issued UNDER q0's
// MFMAs, setprio around MFMA clusters. v5-v8 experiments (P-regs,
// 16-wave block, small tiles, anti-phase blocks) ALL regressed --
// reverted. Counted-vmcnt is the one lever v5-v8 dropped (drain-0).
// ============================================================
__global__ __launch_bounds__(512, 2) void conv3x3_f16_kernel(
    const _Float16* __restrict__ fh, const _Float16* __restrict__ fl,
    const _Float16* __restrict__ wh, const _Float16* __restrict__ wl,
    const float* __restrict__ bias, float* __restrict__ t)
{
    const int id  = blockIdx.x;            // 512 blocks
    const int b   = id & 7;                // b == XCD (dispatch round-robins id%8)
    const int g   = id >> 3;               // 0..63
    const int co0 = (g >> 4) << 7;         // co-major: 16-block windows share weight slice (L2)
    const int pt0 = (g & 15) << 8;         // 16 px-blocks of 256 -> p' 0..4095
    const int tid = threadIdx.x;
    const int w   = tid >> 6;              // 0..7
    const int l   = tid & 63;
    const int wm  = w >> 2, wn = w & 3;    // 2x4 wave grid -> wave tile 64co x 64px
    const int ln  = l & 31, lk = l >> 5;

    __shared__ __align__(16) _Float16 S[5][24][512];   // 120 KB: ring of 5 step-buffers
    // per step-buffer: tiles 0..7 = A (mt*2+hi/lo), 8..23 = B (8 + nt*2 + hi/lo)

    // stage bases: wave w stages tiles 3w..3w+2 (1 KB each, lane-linear dest)
    const _Float16* sb[3];
    u32 ldof[3];
    bool isA[3];
    const long long fbase = (long long)b * NPXP + pt0;
    #pragma unroll
    for (int i = 0; i < 3; ++i) {
        const int ti = w * 3 + i;
        ldof[i] = (u32)(ti * 1024 + l * 16);
        isA[i] = (ti < 8);
        if (ti < 8) {
            const int mt = ti >> 1, hl = ti & 1;
            sb[i] = (hl ? wl : wh) + ((long long)(co0 + (mt << 5) + ln) << 9) + (lk << 3);
        } else {
            const int tj = ti - 8, nt = tj >> 1, hl = tj & 1;
            sb[i] = (hl ? fl : fh) + ((fbase + (nt << 5) + ln) << 9) + (lk << 3);
        }
    }
    char* lbase = (char*)&S[0][0][0];

    auto stage = [&](int q, int slot) {
        const int kk  = q >> 5;                    // 0..8 wave-uniform
        const int ci0 = (q & 31) << 4;
        const long long offA = ((long long)kk << 18) + ci0;
        const int kd = (kk * 11) >> 5;             // kk/3
        const int s  = kd * 77 + kk - 81;          // dy*80 + dx
        const long long offB = ((long long)s << 9) + ci0;
        char* ld = lbase + slot * 24576;
        #pragma unroll
        for (int i = 0; i < 3; ++i) {
            const long long off = isA[i] ? offA : offB;
            GLL16(sb[i] + off, ld + ldof[i]);
        }
    };

    f32x16 acc[2][2], l2[2][2];
    #pragma unroll
    for (int i = 0; i < 2; ++i)
        #pragma unroll
        for (int j = 0; j < 2; ++j)
            #pragma unroll
            for (int gg = 0; gg < 16; ++gg) { acc[i][j][gg] = 0.0f; l2[i][j][gg] = 0.0f; }

    const int ao = l << 3;   // f16 units: lane-linear fragment slice (HW-verified r1)

    auto readFrags = [&](int slot, h8* Ah, h8* Al, h8* Bh, h8* Bl) {
        const _Float16* Sq = (const _Float16*)(lbase + slot * 24576);
        #pragma unroll
        for (int i = 0; i < 2; ++i) {
            const int mt = (wm << 1) + i, nt = (wn << 1) + i;
            Ah[i] = *(const h8*)(Sq + (((mt << 1) + 0) << 9) + ao);
            Al[i] = *(const h8*)(Sq + (((mt << 1) + 1) << 9) + ao);
            Bh[i] = *(const h8*)(Sq + ((8 + (nt << 1) + 0) << 9) + ao);
            Bl[i] = *(const h8*)(Sq + ((8 + (nt << 1) + 1) << 9) + ao);
        }
    };

    // prologue: fill ring slots 0,1,2 (9 GLL/thread); need steps 0,1 landed
    stage(0, 0); stage(1, 1); stage(2, 2);
    asm volatile("s_waitcnt vmcnt(3)" ::: "memory");
    __builtin_amdgcn_sched_barrier(0);
    __builtin_amdgcn_s_barrier();

    int s0 = 0;   // slot of step q0 = 2F  (advances +2 mod 5 per frame)
    for (int F = 0; F < 144; ++F) {
        const int q0 = F << 1;
        int s1 = s0 + 1; if (s1 >= 5) s1 -= 5;
        int s3 = s0 + 3; if (s3 >= 5) s3 -= 5;
        int s4 = s0 + 4; if (s4 >= 5) s4 -= 5;
        if (q0 + 3 < 288) stage(q0 + 3, s3);     // overwrites slot read in frame F-1 (safe)
        if (q0 + 4 < 288) stage(q0 + 4, s4);

        h8 A0h[2], A0l[2], B0h[2], B0l[2];
        h8 A1h[2], A1l[2], B1h[2], B1l[2];
        readFrags(s0, A0h, A0l, B0h, B0l);
        __builtin_amdgcn_s_setprio(1);
        acc[0][0] = __builtin_amdgcn_mfma_f32_32x32x16_f16(A0h[0], B0h[0], acc[0][0], 0, 0, 0);
        acc[0][0] = __builtin_amdgcn_mfma_f32_32x32x16_f16(A0h[0], B0l[0], acc[0][0], 0, 0, 0);
        acc[0][0] = __builtin_amdgcn_mfma_f32_32x32x16_f16(A0l[0], B0h[0], acc[0][0], 0, 0, 0);
        acc[0][1] = __builtin_amdgcn_mfma_f32_32x32x16_f16(A0h[0], B0h[1], acc[0][1], 0, 0, 0);
        acc[0][1] = __builtin_amdgcn_mfma_f32_32x32x16_f16(A0h[0], B0l[1], acc[0][1], 0, 0, 0);
        acc[0][1] = __builtin_amdgcn_mfma_f32_32x32x16_f16(A0l[0], B0h[1], acc[0][1], 0, 0, 0);
        __builtin_amdgcn_s_setprio(0);
        readFrags(s1, A1h, A1l, B1h, B1l);       // q0+1 reads fly under q0's 2nd half
        __builtin_amdgcn_s_setprio(1);
        acc[1][0] = __builtin_amdgcn_mfma_f32_32x32x16_f16(A0h[1], B0h[0], acc[1][0], 0, 0, 0);
        acc[1][0] = __builtin_amdgcn_mfma_f32_32x32x16_f16(A0h[1], B0l[0], acc[1][0], 0, 0, 0);
        acc[1][0] = __builtin_amdgcn_mfma_f32_32x32x16_f16(A0l[1], B0h[0], acc[1][0], 0, 0, 0);
        acc[1][1] = __builtin_amdgcn_mfma_f32_32x32x16_f16(A0h[1], B0h[1], acc[1][1], 0, 0, 0);
        acc[1][1] = __builtin_amdgcn_mfma_f32_32x32x16_f16(A0h[1], B0l[1], acc[1][1], 0, 0, 0);
        acc[1][1] = __builtin_amdgcn_mfma_f32_32x32x16_f16(A0l[1], B0h[1], acc[1][1], 0, 0, 0);
        // step q0+1 (same quadrant order -> accumulation order preserved)
        acc[0][0] = __builtin_amdgcn_mfma_f32_32x32x16_f16(A1h[0], B1h[0], acc[0][0], 0, 0, 0);
        acc[0][0] = __builtin_amdgcn_mfma_f32_32x32x16_f16(A1h[0], B1l[0], acc[0][0], 0, 0, 0);
        acc[0][0] = __builtin_amdgcn_mfma_f32_32x32x16_f16(A1l[0], B1h[0], acc[0][0], 0, 0, 0);
        acc[0][1] = __builtin_amdgcn_mfma_f32_32x32x16_f16(A1h[0], B1h[1], acc[0][1], 0, 0, 0);
        acc[0][1] = __builtin_amdgcn_mfma_f32_32x32x16_f16(A1h[0], B1l[1], acc[0][1], 0, 0, 0);
        acc[0][1] = __builtin_amdgcn_mfma_f32_32x32x16_f16(A1l[0], B1h[1], acc[0][1], 0, 0, 0);
        acc[1][0] = __builtin_amdgcn_mfma_f32_32x32x16_f16(A1h[1], B1h[0], acc[1][0], 0, 0, 0);
        acc[1][0] = __builtin_amdgcn_mfma_f32_32x32x16_f16(A1h[1], B1l[0], acc[1][0], 0, 0, 0);
        acc[1][0] = __builtin_amdgcn_mfma_f32_32x32x16_f16(A1l[1], B1h[0], acc[1][0], 0, 0, 0);
        acc[1][1] = __builtin_amdgcn_mfma_f32_32x32x16_f16(A1h[1], B1h[1], acc[1][1], 0, 0, 0);
        acc[1][1] = __builtin_amdgcn_mfma_f32_32x32x16_f16(A1h[1], B1l[1], acc[1][1], 0, 0, 0);
        acc[1][1] = __builtin_amdgcn_mfma_f32_32x32x16_f16(A1l[1], B1h[1], acc[1][1], 0, 0, 0);
        __builtin_amdgcn_s_setprio(0);

        if (((q0 + 1) & 7) == 7) {   // two-level f32 cascade drain (same points as r2-r8)
            #pragma unroll
            for (int i = 0; i < 2; ++i)
                #pragma unroll
                for (int j = 0; j < 2; ++j) {
                    l2[i][j] += acc[i][j];
                    #pragma unroll
                    for (int gg = 0; gg < 16; ++gg) acc[i][j][gg] = 0.0f;
                }
        }

        if (F < 143) {
            if (q0 + 4 < 288) { asm volatile("s_waitcnt vmcnt(3)" ::: "memory"); }
            else              { asm volatile("s_waitcnt vmcnt(0)" ::: "memory"); }
            __builtin_amdgcn_sched_barrier(0);
            __builtin_amdgcn_s_barrier();
        }
        s0 += 2; if (s0 >= 5) s0 -= 5;
    }

    // runtime D-layout probe (verified in round-1; never trust the doc mapping)
    int rcp[16];
    {
        h8 pa, pb;
        #pragma unroll
        for (int j = 0; j < 8; ++j) { pa[j] = (_Float16)(float)ln; pb[j] = (_Float16)0.0625f; }
        f32x16 pr, pc;
        #pragma unroll
        for (int gg = 0; gg < 16; ++gg) { pr[gg] = 0.0f; pc[gg] = 0.0f; }
        pr = __builtin_amdgcn_mfma_f32_32x32x16_f16(pa, pb, pr, 0, 0, 0);  // D[m][n] = m
        pc = __builtin_amdgcn_mfma_f32_32x32x16_f16(pb, pa, pc, 0, 0, 0);  // D[m][n] = n
        #pragma unroll
        for (int gg = 0; gg < 16; ++gg)
            rcp[gg] = ((int)(pr[gg] + 0.5f)) | (((int)(pc[gg] + 0.5f)) << 8);
    }

    const double dsc = 1.0 / 524288.0;   // 1/(1024*512) exact descale
    #pragma unroll
    for (int i = 0; i < 2; ++i) {
        #pragma unroll
        for (int j = 0; j < 2; ++j) {
            #pragma unroll
            for (int gg = 0; gg < 16; ++gg) {
                const int row = rcp[gg] & 255;
                const int col = rcp[gg] >> 8;
                const int co  = co0 + (wm << 6) + (i << 5) + row;
                const int pp  = pt0 + (wn << 6) + (j << 5) + col;
                const int yy  = pp / 80;
                const int xx  = pp - yy * 80;
                if (yy >= 1 && yy < 51 && xx >= 2 && xx < 78) {
                    const double v = (double)l2[i][j][gg] * dsc + (double)bias[co];
                    t[((size_t)(b * 512 + co)) * NPX + (yy - 1) * 76 + (xx - 2)]
                        = (float)(v > 0.0 ? v : 0.0);
                }
            }
        }
    }
}

// ============================================================
// FALLBACK Kernel 0: weight transpose conv_w[co][ci][ky][kx] -> wt[kk][ci][co] (f32)
// ============================================================
__global__ __launch_bounds__(1024) void wtrans_kernel(const float* __restrict__ cw,
                                                      float* __restrict__ wt) {
    int o = blockIdx.x * 1024 + threadIdx.x;
    if (o >= 512*512*9) return;
    int co = o & 511;
    int ci = (o >> 9) & 511;
    int kk = o >> 18;
    wt[o] = cw[((co << 9) + ci) * 9 + kk];
}

// ============================================================
// FALLBACK Kernel 1: f64 MFMA conv (round-7 structure), t stored f32
// ============================================================
__global__ __launch_bounds__(256, 2) void conv3x3_mfma_kernel(const float* __restrict__ feat,
                                                              const float* __restrict__ wt,
                                                              const float* __restrict__ bias,
                                                              float* __restrict__ t) {
    const int b   = blockIdx.z;
    const int co0 = blockIdx.y << 7;
    const int px0 = blockIdx.x << 6;
    const int tid = threadIdx.x;
    const int w    = tid >> 6;
    const int l    = tid & 63;
    const int quad = l >> 4;
    const int lc   = l & 15;

    __shared__ double BsF[2][1024];

    int rr[4], cc[4];
    {
        d4 pzr = {0.0, 0.0, 0.0, 0.0};
        d4 pzc = {0.0, 0.0, 0.0, 0.0};
        double paM = (double)lc;
        double pbN = (double)lc;
        pzr = __builtin_amdgcn_mfma_f64_16x16x4f64(paM, 1.0, pzr, 0, 0, 0);
        pzc = __builtin_amdgcn_mfma_f64_16x16x4f64(1.0, pbN, pzc, 0, 0, 0);
        #pragma unroll
        for (int g = 0; g < 4; ++g) {
            rr[g] = (((int)pzr[g]) >> 2) & 15;
            cc[g] = (((int)pzc[g]) >> 2) & 15;
        }
    }

    d4 acc[2][4];
    #pragma unroll
    for (int i = 0; i < 2; ++i)
        #pragma unroll
        for (int j = 0; j < 4; ++j) acc[i][j] = (d4){0.0, 0.0, 0.0, 0.0};

    const float* featb = feat + (size_t)b * 512 * NPX;

    const int b_quad = (tid >> 4) & 3;
    const int b_pxl  = ((tid >> 6) << 4) | (tid & 15);
    const int p      = px0 + b_pxl;
    const int py     = p / 76;
    const int px     = p - py * 76;
    const bool pvalid = (p < NPX);

    float vaf[8], vbf[4];
    double a_cur[8];

    auto loadA = [&](int q, float* va) {
        int kk  = q >> 5;
        int ci0 = (q & 31) << 4;
        const float* ap = wt + (((size_t)(kk * 512 + ci0 + quad)) << 9)
                             + co0 + (w << 5) + lc;
        #pragma unroll
        for (int ks = 0; ks < 4; ++ks) {
            va[ks * 2 + 0] = ap[(ks << 11)];
            va[ks * 2 + 1] = ap[(ks << 11) + 16];
        }
    };
    auto loadB = [&](int q, float* vb) {
        int kk  = q >> 5;
        int ci0 = (q & 31) << 4;
        int kd = kk / 3;
        int dy = kd - 1, dx = kk - kd * 3 - 1;
        int iy = py + dy, ix = px + dx;
        bool ok = pvalid && ((unsigned)iy < 50u) && ((unsigned)ix < 76u);
        if (ok) {
            const float* bp = featb + (size_t)(ci0 + b_quad) * NPX + iy * 76 + ix;
            #pragma unroll
            for (int j = 0; j < 4; ++j) vb[j] = bp[(size_t)(j << 2) * NPX];
        } else {
            vb[0] = vb[1] = vb[2] = vb[3] = 0.0f;
        }
    };

    loadA(0, vaf); loadB(0, vbf);
    #pragma unroll
    for (int j = 0; j < 4; ++j) BsF[0][tid + (j << 8)] = (double)vbf[j];
    #pragma unroll
    for (int j = 0; j < 8; ++j) a_cur[j] = (double)vaf[j];
    __syncthreads();

    for (int q = 0; q < 288; ++q) {
        const int cur = q & 1;
        if (q < 287) { loadA(q + 1, vaf); loadB(q + 1, vbf); }
        const double* bb = BsF[cur];
        #pragma unroll
        for (int ks = 0; ks < 4; ++ks) {
            const double* bp = bb + (ks << 8);
            double a0 = a_cur[ks * 2], a1 = a_cur[ks * 2 + 1];
            #pragma unroll
            for (int nt = 0; nt < 4; ++nt) {
                double bv = bp[(nt << 6) + l];
                acc[0][nt] = __builtin_amdgcn_mfma_f64_16x16x4f64(a0, bv, acc[0][nt], 0, 0, 0);
                acc[1][nt] = __builtin_amdgcn_mfma_f64_16x16x4f64(a1, bv, acc[1][nt], 0, 0, 0);
            }
        }
        if (q < 287) {
            #pragma unroll
            for (int j = 0; j < 4; ++j) BsF[cur ^ 1][tid + (j << 8)] = (double)vbf[j];
            #pragma unroll
            for (int j = 0; j < 8; ++j) a_cur[j] = (double)vaf[j];
            __syncthreads();
        }
    }

    #pragma unroll
    for (int mt = 0; mt < 2; ++mt) {
        #pragma unroll
        for (int g = 0; g < 4; ++g) {
            int co = co0 + (w << 5) + (mt << 4) + rr[g];
            double bs = (double)bias[co];
            float* row = t + ((size_t)b * 512 + co) * NPX;
            #pragma unroll
            for (int nt = 0; nt < 4; ++nt) {
                int pp = px0 + (nt << 4) + cc[g];
                if (pp < NPX) {
                    double v = acc[mt][nt][g] + bs;
                    row[pp] = (float)(v > 0.0 ? v : 0.0);
                }
            }
        }
    }
}

// ============================================================
// Kernel 2a: 1x1 heads, split-K x4 partials (f64 accumulate from f32 t)
// ============================================================
__global__ __launch_bounds__(64) void heads_partial_kernel(const float* __restrict__ t,
                                                           const float* __restrict__ cls_w,
                                                           const float* __restrict__ box_w,
                                                           double* __restrict__ part) {
    const int b = blockIdx.y, c = blockIdx.z;
    const int p = blockIdx.x * 64 + threadIdx.x;
    if (p >= NPX) return;
    const float* tb = t + ((size_t)b * 512 + c * 128) * NPX + p;

    double ac[9]  = {};
    double ab[36] = {};
    for (int ci = 0; ci < 128; ++ci) {
        double tv = (double)tb[(size_t)ci * NPX];
        int cw = c * 128 + ci;
        #pragma unroll
        for (int o = 0; o < 9;  ++o) ac[o] = fma((double)cls_w[o * 512 + cw], tv, ac[o]);
        #pragma unroll
        for (int o = 0; o < 36; ++o) ab[o] = fma((double)box_w[o * 512 + cw], tv, ab[o]);
    }
    double* dst = part + ((size_t)(c * 8 + b) * 45) * NPX + p;
    #pragma unroll
    for (int o = 0; o < 9;  ++o) dst[(size_t)o * NPX] = ac[o];
    #pragma unroll
    for (int o = 0; o < 36; ++o) dst[(size_t)(9 + o) * NPX] = ab[o];
}

// shared decode body
__device__ __forceinline__ void decode_px(int b, int p, const double* s45,
                                          const float* cls_b, const float* box_b,
                                          float* out_obj, float* out_del,
                                          float* boxes, u64* items) {
    float* ob = out_obj + (size_t)b * NANCH + (size_t)p * 9;
    float* dl = out_del + (size_t)b * NANCH * 4 + (size_t)p * 36;
    const int yy = p / 76, xx = p - yy * 76;

    #pragma unroll
    for (int a = 0; a < 9; ++a) {
        double s  = s45[a] + (double)cls_b[a];
        ob[a] = (float)s;
        double d0 = s45[9 + 4*a + 0] + (double)box_b[4*a+0];
        double d1 = s45[9 + 4*a + 1] + (double)box_b[4*a+1];
        double d2 = s45[9 + 4*a + 2] + (double)box_b[4*a+2];
        double d3 = s45[9 + 4*a + 3] + (double)box_b[4*a+3];
        dl[4*a+0] = (float)d0; dl[4*a+1] = (float)d1;
        dl[4*a+2] = (float)d2; dl[4*a+3] = (float)d3;

        int si = a / 3, ri = a - si * 3;
        double sz = (si == 0) ? 128.0 : ((si == 1) ? 256.0 : 512.0);
        double hr = (ri == 0) ? 0.7071067811865476 : ((ri == 1) ? 1.0 : 1.4142135623730951);
        float bx2f = (float)(sz / hr * 0.5);
        float by2f = (float)(sz * hr * 0.5);

        double sx = (double)(xx * 16), sy = (double)(yy * 16);
        double x1 = sx - (double)bx2f, x2 = sx + (double)bx2f;
        double y1 = sy - (double)by2f, y2 = sy + (double)by2f;

        double wa = x2 - x1, ha = y2 - y1;
        double cxa = x1 + 0.5 * wa, cya = y1 + 0.5 * ha;
        double cx = d0 * wa + cxa, cy = d1 * ha + cya;
        double w  = exp(d2) * wa,  h  = exp(d3) * ha;

        double px1 = cx - 0.5 * w, py1 = cy - 0.5 * h;
        double px2 = cx + 0.5 * w, py2 = cy + 0.5 * h;
        px1 = fmin(fmax(px1, 0.0), 1216.0);
        py1 = fmin(fmax(py1, 0.0), 800.0);
        px2 = fmin(fmax(px2, 0.0), 1216.0);
        py2 = fmin(fmax(py2, 0.0), 800.0);

        bool keep = ((px2 - px1) >= 16.0) && ((py2 - py1) >= 16.0);
        double se = keep ? s : -INFINITY;

        u64 ubits = (u64)__double_as_longlong(se);
        u64 ka = (ubits >> 63) ? ~ubits : (ubits | 0x8000000000000000ull);
        u64 kd = ~ka;
        int n = p * 9 + a;
        items[(size_t)b * NANCH + n] = (kd & ~0xFFFFull) | (u64)(u32)n;
        *(float4*)(boxes + ((size_t)b * NANCH + n) * 4) =
            make_float4((float)px1, (float)py1, (float)px2, (float)py2);
    }
}

// ============================================================
// Kernel 2b: reduce partials (c ascending, deterministic) + decode
// ============================================================
__global__ __launch_bounds__(64) void reduce_decode_kernel(const double* __restrict__ part,
                                                           const float* __restrict__ cls_b,
                                                           const float* __restrict__ box_b,
                                                           float* __restrict__ out_obj,
                                                           float* __restrict__ out_del,
                                                           float* __restrict__ boxes,
                                                           u64* __restrict__ items) {
    const int b = blockIdx.y;
    const int p = blockIdx.x * 64 + threadIdx.x;
    if (p >= NPX) return;
    double s45[45];
    #pragma unroll
    for (int o = 0; o < 45; ++o) {
        double s = part[((size_t)(0 * 8 + b) * 45 + o) * NPX + p];
        s += part[((size_t)(1 * 8 + b) * 45 + o) * NPX + p];
        s += part[((size_t)(2 * 8 + b) * 45 + o) * NPX + p];
        s += part[((size_t)(3 * 8 + b) * 45 + o) * NPX + p];
        s45[o] = s;
    }
    decode_px(b, p, s45, cls_b, box_b, out_obj, out_del, boxes, items);
}

// ============================================================
// Kernel 2-fallback: single-stage heads+decode (if ws too small)
// ============================================================
__global__ __launch_bounds__(256) void heads_decode_kernel(const float* __restrict__ t,
                                                           const float* __restrict__ cls_w,
                                                           const float* __restrict__ cls_b,
                                                           const float* __restrict__ box_w,
                                                           const float* __restrict__ box_b,
                                                           float* __restrict__ out_obj,
                                                           float* __restrict__ out_del,
                                                           float* __restrict__ boxes,
                                                           u64* __restrict__ items) {
    const int b = blockIdx.y;
    const int p = blockIdx.x * 256 + threadIdx.x;
    if (p >= NPX) return;
    const float* tb = t + (size_t)b * 512 * NPX + p;
    double s45[45];
    #pragma unroll
    for (int o = 0; o < 45; ++o) s45[o] = 0.0;
    for (int ci = 0; ci < 512; ++ci) {
        double tv = (double)tb[(size_t)ci * NPX];
        #pragma unroll
        for (int o = 0; o < 9;  ++o) s45[o]     = fma((double)cls_w[o * 512 + ci], tv, s45[o]);
        #pragma unroll
        for (int o = 0; o < 36; ++o) s45[9 + o] = fma((double)box_w[o * 512 + ci], tv, s45[9 + o]);
    }
    decode_px(b, p, s45, cls_b, box_b, out_obj, out_del, boxes, items);
}

// ============================================================
// IoU > 0.7 test (f32, matches reference formula)
// ============================================================
__device__ __forceinline__ bool iou_gt(float4 A, float4 B, float areaA, float areaB) {
    float ix1 = fmaxf(A.x, B.x), iy1 = fmaxf(A.y, B.y);
    float ix2 = fminf(A.z, B.z), iy2 = fminf(A.w, B.w);
    float iw = fmaxf(ix2 - ix1, 0.0f), ih = fmaxf(iy2 - iy1, 0.0f);
    float inter = iw * ih;
    float uni = areaA + areaB - inter;
    float iou = (uni > 0.0f) ? (inter / uni) : 0.0f;
    return iou > 0.7f;
}

// ============================================================
// Kernel 3: fused top-6000 select + bitonic sort + serial-scan NMS
// ============================================================
__global__ __launch_bounds__(1024) void topk_nms_kernel(const u64* __restrict__ items,
                                                        const float* __restrict__ boxes,
                                                        float* __restrict__ out) {
    extern __shared__ u64 buf[];
    u32* hist = (u32*)buf;
    u32* scan = hist + 4096;
    u32* scal = hist + 5120;

    const int b   = blockIdx.x;
    const int tid = threadIdx.x;
    const u64* it = items + (size_t)b * NANCH;

    #pragma unroll
    for (int i = 0; i < 4; ++i) hist[tid * 4 + i] = 0;
    __syncthreads();
    for (int i = tid; i < NANCH; i += 1024)
        atomicAdd(&hist[(u32)(it[i] >> 52)], 1);
    __syncthreads();

    u32 B1, cum1;
    {
        u32 c0 = hist[tid*4], c1 = hist[tid*4+1], c2 = hist[tid*4+2], c3 = hist[tid*4+3];
        u32 S = c0 + c1 + c2 + c3;
        scan[tid] = S;
        __syncthreads();
        for (int off = 1; off < 1024; off <<= 1) {
            u32 v = (tid >= off) ? scan[tid - off] : 0;
            __syncthreads();
            scan[tid] += v;
            __syncthreads();
        }
        u32 excl = scan[tid] - S;
        const u32 target = 5999;
        if (target >= excl && target < excl + S) {
            u32 pfx = excl, bidx, cum;
            if      (target < pfx + c0)           { bidx = tid*4;   cum = pfx; }
            else if (target < pfx + c0 + c1)      { bidx = tid*4+1; cum = pfx + c0; }
            else if (target < pfx + c0 + c1 + c2) { bidx = tid*4+2; cum = pfx + c0 + c1; }
            else                                  { bidx = tid*4+3; cum = pfx + c0 + c1 + c2; }
            scal[0] = bidx; scal[1] = cum;
        }
    }
    __syncthreads();
    B1 = scal[0]; cum1 = scal[1];
    __syncthreads();

    #pragma unroll
    for (int i = 0; i < 4; ++i) hist[tid * 4 + i] = 0;
    __syncthreads();
    for (int i = tid; i < NANCH; i += 1024) {
        u64 v = it[i];
        if ((u32)(v >> 52) == B1)
            atomicAdd(&hist[(u32)(v >> 40) & 0xFFF], 1);
    }
    __syncthreads();

    u32 B2;
    {
        u32 c0 = hist[tid*4], c1 = hist[tid*4+1], c2 = hist[tid*4+2], c3 = hist[tid*4+3];
        u32 S = c0 + c1 + c2 + c3;
        scan[tid] = S;
        __syncthreads();
        for (int off = 1; off < 1024; off <<= 1) {
            u32 v = (tid >= off) ? scan[tid - off] : 0;
            __syncthreads();
            scan[tid] += v;
            __syncthreads();
        }
        u32 excl = scan[tid] - S;
        const u32 target = 5999 - cum1;
        if (target >= excl && target < excl + S) {
            u32 pfx = excl, bidx;
            if      (target < pfx + c0)           bidx = tid*4;
            else if (target < pfx + c0 + c1)      bidx = tid*4+1;
            else if (target < pfx + c0 + c1 + c2) bidx = tid*4+2;
            else                                  bidx = tid*4+3;
            scal[2] = bidx;
        }
    }
    __syncthreads();
    B2 = scal[2];
    const u32 T = ((B1 << 12) | B2) + 1;
    __syncthreads();

    for (int i = tid; i < 8192; i += 1024) buf[i] = ~0ull;
    __syncthreads();
    u32* cnt = (u32*)&buf[8191];
    if (tid == 0) *cnt = 0;
    __syncthreads();
    for (int i = tid; i < NANCH; i += 1024) {
        u64 v = it[i];
        if ((u32)(v >> 40) < T) {
            u32 pos = atomicAdd(cnt, 1);
            if (pos < 8191) buf[pos] = v;
        }
    }
    __syncthreads();
    if (tid == 0) buf[8191] = ~0ull;
    __syncthreads();

    for (int size = 2; size <= 8192; size <<= 1) {
        for (int stride = size >> 1; stride > 0; stride >>= 1) {
            #pragma unroll
            for (int v = 0; v < 4; ++v) {
                int idx = tid + (v << 10);
                int i = 2 * idx - (idx & (stride - 1));
                int j = i + stride;
                bool up = ((i & size) == 0);
                u64 x = buf[i], y = buf[j];
                if ((x > y) == up) { buf[i] = y; buf[j] = x; }
            }
            __syncthreads();
        }
    }

    float4 bx6[6]; u32 dead6[6];
    #pragma unroll
    for (int s = 0; s < 6; ++s) {
        int r = tid + (s << 10);
        u64 v = buf[r];
        bool dd = (r >= NSEL) || ((u32)(v >> 32) >= 0xFFF00000u);
        float4 bb = make_float4(0.f, 0.f, 0.f, 0.f);
        if (!dd) {
            u32 n = (u32)(v & 0xFFFFull);
            bb = *(const float4*)(boxes + ((size_t)b * NANCH + n) * 4);
        }
        bx6[s] = bb;
        dead6[s] = dd ? 1u : 0u;
    }
    __syncthreads();

    float4* candbox = (float4*)buf;
    u64*    wmask   = (u64*)(buf + 2560);
    float4* accb    = (float4*)(buf + 3072);
    u32*    cntp    = (u32*)(buf + 3712);
    if (tid == 0) *cntp = 0;
    __syncthreads();

    for (int s = 0; s < 6; ++s) {
        int count = (int)*cntp;
        if (count >= NOUT) break;
        float4 mb = bx6[s];
        float  ma = (mb.z - mb.x) * (mb.w - mb.y);
        bool dd = dead6[s] != 0;
        for (int a2 = 0; a2 < count && !dd; ++a2) {
            float4 abx = accb[a2];
            if (iou_gt(mb, abx, ma, (abx.z - abx.x) * (abx.w - abx.y))) dd = true;
        }
        candbox[tid] = mb;
        u64 bal = __ballot(!dd);
        if ((tid & 63) == 0) wmask[tid >> 6] = bal;
        __syncthreads();
        if (tid < 64) {
            int cnt2 = count;
            for (int w2 = 0; w2 < 16 && cnt2 < NOUT; ++w2) {
                u64 mm = wmask[w2];
                while (mm != 0 && cnt2 < NOUT) {
                    int bit = __ffsll(mm) - 1;
                    mm &= (mm - 1);
                    float4 cb = candbox[(w2 << 6) + bit];
                    float  ca = (cb.z - cb.x) * (cb.w - cb.y);
                    bool okc = true;
                    for (int base = count; base < cnt2 && okc; base += 64) {
                        int idx = base + tid;
                        bool bad = false;
                        if (idx < cnt2) {
                            float4 abx = accb[idx];
                            bad = iou_gt(cb, abx, ca, (abx.z - abx.x) * (abx.w - abx.y));
                        }
                        if (__any(bad)) okc = false;
                    }
                    if (okc) {
                        if (tid == 0) accb[cnt2] = cb;
                        cnt2++;
                    }
                }
            }
            if (tid == 0) *cntp = (u32)cnt2;
        }
        __syncthreads();
    }

    int fin = (int)*cntp;
    for (int r = tid; r < NOUT; r += 1024) {
        float4 v = (r < fin) ? accb[r] : make_float4(0.f, 0.f, 0.f, 0.f);
        *(float4*)(out + ((size_t)b * NOUT + r) * 4) = v;
    }
}

// ============================================================
extern "C" void kernel_launch(void* const* d_in, const int* in_sizes, int n_in,
                              void* d_out, int out_size, void* d_ws, size_t ws_size,
                              hipStream_t stream) {
    const float* feat   = (const float*)d_in[0];
    const float* conv_w = (const float*)d_in[1];
    const float* conv_b = (const float*)d_in[2];
    const float* cls_w  = (const float*)d_in[3];
    const float* cls_b  = (const float*)d_in[4];
    const float* box_w  = (const float*)d_in[5];
    const float* box_b  = (const float*)d_in[6];

    float* out       = (float*)d_out;
    float* out_props = out;                       // [8][300][4]
    float* out_obj   = out + 9600;                // [8][34200]
    float* out_del   = out + 9600 + 273600;       // [8][34200][4]

    char* ws = (char*)d_ws;
    float*    t     = (float*)(ws + OFF_T);
    _Float16* wth   = (_Float16*)(ws + OFF_WTH);
    _Float16* wtl   = (_Float16*)(ws + OFF_WTL);
    float*    wtf   = (float*)(ws + OFF_WTH);      // fallback f32 wt (spans hi+lo region)
    float*    boxes = (float*)(ws + OFF_BOXES);
    u64*      items = (u64*)(ws + OFF_ITEMS);
    _Float16* fsph  = (_Float16*)(ws + OFF_FSPH);
    _Float16* fspl  = (_Float16*)(ws + OFF_FSPL);
    double*   part  = (double*)(ws + OFF_PART);

    if (ws_size >= WS_NEED_F16) {
        hipLaunchKernelGGL(prep_kernel, dim3(16941), dim3(256), 0, stream,
                           feat, conv_w, wth, wtl, fsph, fspl);
        hipLaunchKernelGGL(conv3x3_f16_kernel, dim3(512), dim3(512), 0, stream,
                           fsph, fspl, wth, wtl, conv_b, t);
    } else {
        hipLaunchKernelGGL(wtrans_kernel, dim3(2304), dim3(1024), 0, stream, conv_w, wtf);
        hipLaunchKernelGGL(conv3x3_mfma_kernel, dim3(60, 4, 8), dim3(256), 0, stream,
                           feat, wtf, conv_b, t);
    }
    if (ws_size >= WS_NEED_SPLITK) {
        hipLaunchKernelGGL(heads_partial_kernel, dim3(60, 8, 4), dim3(64), 0, stream,
                           t, cls_w, box_w, part);
        hipLaunchKernelGGL(reduce_decode_kernel, dim3(60, 8), dim3(64), 0, stream,
                           part, cls_b, box_b, out_obj, out_del, boxes, items);
    } else {
        hipLaunchKernelGGL(heads_decode_kernel, dim3(15, 8), dim3(256), 0, stream,
                           t, cls_w, cls_b, box_w, box_b, out_obj, out_del, boxes, items);
    }
    hipLaunchKernelGGL(topk_nms_kernel, dim3(8), dim3(1024), 65536, stream,
                       items, boxes, out_props);
}